// Round 15
// baseline (88.059 us; speedup 1.0000x reference)
//
#include <hip/hip_runtime.h>
#include <math.h>

#define COND_C 6
#define NOUT 11   // N_MODES*DIM*2 + N_MODES + 1

typedef float f32x2 __attribute__((ext_vector_type(2)));

static constexpr float LOG2E         = 1.44269504088896340736f;
static constexpr float LN2           = 0.69314718055994530942f;
static constexpr float INV_2PI       = 0.15915494309189533577f;
static constexpr float NEG_HALF_L2E  = -0.72134752044448170368f;  // -0.5*log2(e)
static constexpr float INV_PI        = 0.31830988618f;

// packed-weight layout in d_ws (floats):
//   [0..255]    W1T: row j (32 rows) = {W1[0][j]..W1[5][j], b1[j], 0}   (8 floats)
//   [256..639]  W2p: row j (32 rows) = {W2[j][0]..W2[j][10], 0}          (12 floats)
//   [640..651]  b2p: {b2[0]..b2[10], 0}
#define WS_W2_OFF 256
#define WS_B2_OFF 640
#define WS_FLOATS 656

__device__ __forceinline__ float rcp_f(float x)  { return __builtin_amdgcn_rcpf(x); }
__device__ __forceinline__ float exp2_f(float x) { return __builtin_amdgcn_exp2f(x); }
__device__ __forceinline__ float log2_f(float x) { return __builtin_amdgcn_logf(x); }
__device__ __forceinline__ float sqrt_f(float x) { return __builtin_amdgcn_sqrtf(x); }
// v_sin_f32 / v_cos_f32 take input in REVOLUTIONS: sin_rev(x) = sin(2*pi*x)
__device__ __forceinline__ float sin_rev(float x) { return __builtin_amdgcn_sinf(x); }
__device__ __forceinline__ float cos_rev(float x) { return __builtin_amdgcn_cosf(x); }

__device__ __forceinline__ f32x2 fma2(f32x2 a, f32x2 b, f32x2 c) {
    return __builtin_elementwise_fma(a, b, c);
}
__device__ __forceinline__ f32x2 bc2(float w) { return (f32x2){w, w}; }

struct RowOut { float z0, z1, lp; };

// Per-row epilogue: sampling + log-density (product form, merged trig).
__device__ __forceinline__ RowOut epilogue(const float* o, float rdn, float u1)
{
    float loc00 = o[0], loc01 = o[1], loc10 = o[2], loc11 = o[3];
    float ls00  = o[4], ls01  = o[5], ls10  = o[6], ls11  = o[7];
    float aw0 = fabsf(o[8]), aw1 = fabsf(o[9]), aw2 = fabsf(o[10]);
    float rinv = rcp_f(aw0 + aw1 + aw2);
    float w0 = aw0 * rinv, w1 = aw1 * rinv, w2 = aw2 * rinv;

    float wc0 = w0;
    float wc1 = w0 + w1;
    bool g1 = rdn < wc0;
    bool g2 = (!g1) && (rdn < wc1);
    bool gauss = g1 || g2;

    float num = rdn - (g1 ? 0.0f : (g2 ? wc0 : wc1));
    float den = g1 ? wc0 : (g2 ? w1 : w2);
    float u0  = num * rcp_f(den);

    // Box-Muller radius (gauss only; harmless otherwise)
    float U1 = gauss ? u0 : 0.5f;
    float R = sqrt_f(-1.38629436111989062f * log2_f(U1));  // sqrt(-2 ln U1)

    // Lambert geometry
    float wo0 = fmaf(2.0f, u0, -1.0f);
    float wo1 = fmaf(2.0f, u1, -1.0f);
    bool c1b = (fabsf(wo0) > fabsf(wo1)) && !((wo0 == 0.0f) && (wo1 == 0.0f));
    float sden = c1b ? wo0 : ((wo1 == 0.0f) ? 1.0f : wo1);
    float rnum = c1b ? wo1 : wo0;
    float r = rnum * rcp_f(sden);
    float a_rev = c1b ? (0.125f * r) : fmaf(-0.125f, r, 0.25f);
    float amp = c1b ? wo0 : wo1;   // both-zero -> amp = 0 -> z = 0

    // merged trig: gauss angle = u1 rev; lambert angle = a_rev
    float angle = gauss ? u1 : a_rev;
    float ca = cos_rev(angle);
    float sa = sin_rev(angle);

    // inverse scales (needed for density anyway)
    float ie00 = exp2_f(-ls00 * LOG2E), ie01 = exp2_f(-ls01 * LOG2E);
    float ie10 = exp2_f(-ls10 * LOG2E), ie11 = exp2_f(-ls11 * LOG2E);

    // z = A*{cos,sin}(angle) + B
    float scale0 = rcp_f(g2 ? ie10 : ie00);   // exp(ls_sel0)
    float scale1 = rcp_f(g2 ? ie11 : ie01);
    float A0 = gauss ? (R * scale0) : amp;
    float A1 = gauss ? (R * scale1) : amp;
    float B0 = gauss ? (g2 ? loc10 : loc00) : 0.0f;
    float B1 = gauss ? (g2 ? loc11 : loc01) : 0.0f;
    float z0 = fmaf(A0, ca, B0);
    float z1 = fmaf(A1, sa, B1);

    // log density, product form
    float e00 = (z0 - loc00) * ie00;
    float e01 = (z1 - loc01) * ie01;
    float e10 = (z0 - loc10) * ie10;
    float e11 = (z1 - loc11) * ie11;
    float q0 = fmaf(e00, e00, e01 * e01);
    float q1 = fmaf(e10, e10, e11 * e11);
    float p0 = (w0 + 1e-5f) * INV_2PI * (ie00 * ie01) * exp2_f(NEG_HALF_L2E * q0);
    float p1 = (w1 + 1e-5f) * INV_2PI * (ie10 * ie11) * exp2_f(NEG_HALF_L2E * q1);
    bool invalid = fmaf(z0, z0, z1 * z1) > 1.0f;
    float pl = invalid ? 1e-5f : (INV_PI + 1e-5f);
    float p2 = pl * w2;

    RowOut out;
    out.z0 = z0; out.z1 = z1;
    out.lp = log2_f(p0 + p1 + p2) * LN2;
    return out;
}

// ---- setup: repack weights into d_ws for float4 immediate-offset access ----
__global__ void pack_weights_kernel(const float* __restrict__ W1,
                                    const float* __restrict__ b1,
                                    const float* __restrict__ W2,
                                    const float* __restrict__ b2,
                                    float* __restrict__ ws)
{
    int t = threadIdx.x;   // one block of 672
    if (t < 256) {         // W1T + b1: ws[j*8 + c]
        int j = t >> 3, c = t & 7;
        ws[t] = (c < 6) ? W1[c * 32 + j] : ((c == 6) ? b1[j] : 0.0f);
    } else if (t < 640) {  // W2 padded rows: ws[256 + j*12 + k]
        int u = t - 256;
        int j = u / 12, k = u - j * 12;
        ws[t] = (k < 11) ? W2[j * 11 + k] : 0.0f;
    } else if (t < WS_FLOATS) {
        int k = t - WS_B2_OFF;
        ws[t] = (k < 11) ? b2[k] : 0.0f;
    }
}

__global__ __launch_bounds__(256)
void gmm_weighted_cond_kernel(const float* __restrict__ cond,
                              const float* __restrict__ seed,
                              const float* __restrict__ ws,
                              float* __restrict__ z_out,
                              float* __restrict__ logp_out,
                              int Npairs)
{
    int t = blockIdx.x * blockDim.x + threadIdx.x;
    if (t >= Npairs) return;

    const float4* W1T = reinterpret_cast<const float4*>(ws);                 // 2 float4 per j
    const float4* W2p = reinterpret_cast<const float4*>(ws + WS_W2_OFF);     // 3 float4 per j
    const float4* b2p = reinterpret_cast<const float4*>(ws + WS_B2_OFF);     // 3 float4

    // ---- load 2 rows of cond + seeds ----
    const float4* cp = reinterpret_cast<const float4*>(cond) + (size_t)t * 3;
    float4 ca = cp[0], cb = cp[1], cc = cp[2];
    float4 sd = reinterpret_cast<const float4*>(seed)[t];

    // row A: ca.x ca.y ca.z ca.w cb.x cb.y ; row B: cb.z cb.w cc.x cc.y cc.z cc.w
    f32x2 x0 = {ca.x, cb.z}, x1 = {ca.y, cb.w}, x2 = {ca.z, cc.x};
    f32x2 x3 = {ca.w, cc.y}, x4 = {cb.x, cc.z}, x5 = {cb.y, cc.w};

    // ---- per-wave rotation of the j-order (commutative sum over j).
    // Co-resident waves start at different weight lines, desynchronizing
    // their per-iteration scalar-load bursts and wait windows. woff is
    // wave-uniform, so weight reads stay scalar (s_load). ----
    int woff = ((threadIdx.x >> 6) & 3) * 8 + (blockIdx.x & 1) * 4;

    f32x2 o[NOUT];
    {
        float4 bq0 = b2p[0], bq1 = b2p[1], bq2 = b2p[2];
        o[0] = bc2(bq0.x); o[1] = bc2(bq0.y); o[2]  = bc2(bq0.z); o[3] = bc2(bq0.w);
        o[4] = bc2(bq1.x); o[5] = bc2(bq1.y); o[6]  = bc2(bq1.z); o[7] = bc2(bq1.w);
        o[8] = bc2(bq2.x); o[9] = bc2(bq2.y); o[10] = bc2(bq2.z);
    }
#pragma unroll 1
    for (int j = 0; j < 32; ++j) {
        int jj = (j + woff) & 31;
        float4 wa = W1T[jj * 2];        // W1[0..3][jj]
        float4 wb = W1T[jj * 2 + 1];    // W1[4][jj], W1[5][jj], b1[jj], 0
        f32x2 acc = bc2(wb.z);
        acc = fma2(x0, bc2(wa.x), acc);
        acc = fma2(x1, bc2(wa.y), acc);
        acc = fma2(x2, bc2(wa.z), acc);
        acc = fma2(x3, bc2(wa.w), acc);
        acc = fma2(x4, bc2(wb.x), acc);
        acc = fma2(x5, bc2(wb.y), acc);
        acc = __builtin_elementwise_max(acc, (f32x2){0.0f, 0.0f});

        float4 q0 = W2p[jj * 3];
        float4 q1 = W2p[jj * 3 + 1];
        float4 q2 = W2p[jj * 3 + 2];
        o[0]  = fma2(acc, bc2(q0.x), o[0]);
        o[1]  = fma2(acc, bc2(q0.y), o[1]);
        o[2]  = fma2(acc, bc2(q0.z), o[2]);
        o[3]  = fma2(acc, bc2(q0.w), o[3]);
        o[4]  = fma2(acc, bc2(q1.x), o[4]);
        o[5]  = fma2(acc, bc2(q1.y), o[5]);
        o[6]  = fma2(acc, bc2(q1.z), o[6]);
        o[7]  = fma2(acc, bc2(q1.w), o[7]);
        o[8]  = fma2(acc, bc2(q2.x), o[8]);
        o[9]  = fma2(acc, bc2(q2.y), o[9]);
        o[10] = fma2(acc, bc2(q2.z), o[10]);
    }

    float oA[NOUT], oB[NOUT];
#pragma unroll
    for (int k = 0; k < NOUT; ++k) { oA[k] = o[k].x; oB[k] = o[k].y; }

    RowOut rA = epilogue(oA, sd.x, sd.y);
    RowOut rB = epilogue(oB, sd.z, sd.w);

    // ---- stores: z (N,2) as float4 per pair, log_p as float2 ----
    reinterpret_cast<float4*>(z_out)[t] = make_float4(rA.z0, rA.z1, rB.z0, rB.z1);
    reinterpret_cast<float2*>(logp_out)[t] = make_float2(rA.lp, rB.lp);
}

extern "C" void kernel_launch(void* const* d_in, const int* in_sizes, int n_in,
                              void* d_out, int out_size, void* d_ws, size_t ws_size,
                              hipStream_t stream)
{
    const float* cond = (const float*)d_in[0];
    const float* seed = (const float*)d_in[1];
    const float* W1   = (const float*)d_in[2];
    const float* b1   = (const float*)d_in[3];
    const float* W2   = (const float*)d_in[4];
    const float* b2   = (const float*)d_in[5];

    int N = in_sizes[1] / 2;   // randseed is (N,2)
    int Npairs = N / 2;

    float* ws = (float*)d_ws;
    float* z_out    = (float*)d_out;                   // first 2N floats
    float* logp_out = (float*)d_out + 2 * (size_t)N;   // next N floats

    pack_weights_kernel<<<1, 672, 0, stream>>>(W1, b1, W2, b2, ws);

    int block = 256;
    int grid = (Npairs + block - 1) / block;
    gmm_weighted_cond_kernel<<<grid, block, 0, stream>>>(
        cond, seed, ws, z_out, logp_out, Npairs);
}

// Round 16
// 44.222 us; speedup vs baseline: 1.9913x; 1.9913x over previous
//
#include <hip/hip_runtime.h>
#include <math.h>

#define COND_C 6
#define NOUT 11   // N_MODES*DIM*2 + N_MODES + 1

typedef float f32x2 __attribute__((ext_vector_type(2)));

static constexpr float LOG2E         = 1.44269504088896340736f;
static constexpr float LN2           = 0.69314718055994530942f;
static constexpr float INV_2PI       = 0.15915494309189533577f;
static constexpr float NEG_HALF_L2E  = -0.72134752044448170368f;  // -0.5*log2(e)
static constexpr float INV_PI        = 0.31830988618f;

// packed-weight layout in d_ws (floats):
//   [0..255]    W1T: row j (32 rows) = {W1[0][j]..W1[5][j], b1[j], 0}   (8 floats)
//   [256..639]  W2p: row j (32 rows) = {W2[j][0]..W2[j][10], 0}          (12 floats)
//   [640..651]  b2p: {b2[0]..b2[10], 0}
#define WS_W2_OFF 256
#define WS_B2_OFF 640
#define WS_FLOATS 656

__device__ __forceinline__ float rcp_f(float x)  { return __builtin_amdgcn_rcpf(x); }
__device__ __forceinline__ float exp2_f(float x) { return __builtin_amdgcn_exp2f(x); }
__device__ __forceinline__ float log2_f(float x) { return __builtin_amdgcn_logf(x); }
__device__ __forceinline__ float sqrt_f(float x) { return __builtin_amdgcn_sqrtf(x); }
// v_sin_f32 / v_cos_f32 take input in REVOLUTIONS: sin_rev(x) = sin(2*pi*x)
__device__ __forceinline__ float sin_rev(float x) { return __builtin_amdgcn_sinf(x); }
__device__ __forceinline__ float cos_rev(float x) { return __builtin_amdgcn_cosf(x); }

__device__ __forceinline__ f32x2 fma2(f32x2 a, f32x2 b, f32x2 c) {
    return __builtin_elementwise_fma(a, b, c);
}
__device__ __forceinline__ f32x2 bc2(float w) { return (f32x2){w, w}; }

struct RowOut { float z0, z1, lp; };

// Per-row epilogue: sampling + log-density (product form, merged trig).
__device__ __forceinline__ RowOut epilogue(const float* o, float rdn, float u1)
{
    float loc00 = o[0], loc01 = o[1], loc10 = o[2], loc11 = o[3];
    float ls00  = o[4], ls01  = o[5], ls10  = o[6], ls11  = o[7];
    float aw0 = fabsf(o[8]), aw1 = fabsf(o[9]), aw2 = fabsf(o[10]);
    float rinv = rcp_f(aw0 + aw1 + aw2);
    float w0 = aw0 * rinv, w1 = aw1 * rinv, w2 = aw2 * rinv;

    float wc0 = w0;
    float wc1 = w0 + w1;
    bool g1 = rdn < wc0;
    bool g2 = (!g1) && (rdn < wc1);
    bool gauss = g1 || g2;

    float num = rdn - (g1 ? 0.0f : (g2 ? wc0 : wc1));
    float den = g1 ? wc0 : (g2 ? w1 : w2);
    float u0  = num * rcp_f(den);

    // Box-Muller radius (gauss only; harmless otherwise)
    float U1 = gauss ? u0 : 0.5f;
    float R = sqrt_f(-1.38629436111989062f * log2_f(U1));  // sqrt(-2 ln U1)

    // Lambert geometry
    float wo0 = fmaf(2.0f, u0, -1.0f);
    float wo1 = fmaf(2.0f, u1, -1.0f);
    bool c1b = (fabsf(wo0) > fabsf(wo1)) && !((wo0 == 0.0f) && (wo1 == 0.0f));
    float sden = c1b ? wo0 : ((wo1 == 0.0f) ? 1.0f : wo1);
    float rnum = c1b ? wo1 : wo0;
    float r = rnum * rcp_f(sden);
    float a_rev = c1b ? (0.125f * r) : fmaf(-0.125f, r, 0.25f);
    float amp = c1b ? wo0 : wo1;   // both-zero -> amp = 0 -> z = 0

    // merged trig: gauss angle = u1 rev; lambert angle = a_rev
    float angle = gauss ? u1 : a_rev;
    float ca = cos_rev(angle);
    float sa = sin_rev(angle);

    // inverse scales (needed for density anyway)
    float ie00 = exp2_f(-ls00 * LOG2E), ie01 = exp2_f(-ls01 * LOG2E);
    float ie10 = exp2_f(-ls10 * LOG2E), ie11 = exp2_f(-ls11 * LOG2E);

    // z = A*{cos,sin}(angle) + B
    float scale0 = rcp_f(g2 ? ie10 : ie00);   // exp(ls_sel0)
    float scale1 = rcp_f(g2 ? ie11 : ie01);
    float A0 = gauss ? (R * scale0) : amp;
    float A1 = gauss ? (R * scale1) : amp;
    float B0 = gauss ? (g2 ? loc10 : loc00) : 0.0f;
    float B1 = gauss ? (g2 ? loc11 : loc01) : 0.0f;
    float z0 = fmaf(A0, ca, B0);
    float z1 = fmaf(A1, sa, B1);

    // log density, product form
    float e00 = (z0 - loc00) * ie00;
    float e01 = (z1 - loc01) * ie01;
    float e10 = (z0 - loc10) * ie10;
    float e11 = (z1 - loc11) * ie11;
    float q0 = fmaf(e00, e00, e01 * e01);
    float q1 = fmaf(e10, e10, e11 * e11);
    float p0 = (w0 + 1e-5f) * INV_2PI * (ie00 * ie01) * exp2_f(NEG_HALF_L2E * q0);
    float p1 = (w1 + 1e-5f) * INV_2PI * (ie10 * ie11) * exp2_f(NEG_HALF_L2E * q1);
    bool invalid = fmaf(z0, z0, z1 * z1) > 1.0f;
    float pl = invalid ? 1e-5f : (INV_PI + 1e-5f);
    float p2 = pl * w2;

    RowOut out;
    out.z0 = z0; out.z1 = z1;
    out.lp = log2_f(p0 + p1 + p2) * LN2;
    return out;
}

// ---- setup: repack weights into d_ws for float4 immediate-offset access ----
__global__ void pack_weights_kernel(const float* __restrict__ W1,
                                    const float* __restrict__ b1,
                                    const float* __restrict__ W2,
                                    const float* __restrict__ b2,
                                    float* __restrict__ ws)
{
    int t = threadIdx.x;   // one block of 672
    if (t < 256) {         // W1T + b1: ws[j*8 + c]
        int j = t >> 3, c = t & 7;
        ws[t] = (c < 6) ? W1[c * 32 + j] : ((c == 6) ? b1[j] : 0.0f);
    } else if (t < 640) {  // W2 padded rows: ws[256 + j*12 + k]
        int u = t - 256;
        int j = u / 12, k = u - j * 12;
        ws[t] = (k < 11) ? W2[j * 11 + k] : 0.0f;
    } else if (t < WS_FLOATS) {
        int k = t - WS_B2_OFF;
        ws[t] = (k < 11) ? b2[k] : 0.0f;
    }
}

__global__ __launch_bounds__(256)
void gmm_weighted_cond_kernel(const float* __restrict__ cond,
                              const float* __restrict__ seed,
                              const float* __restrict__ ws,
                              float* __restrict__ z_out,
                              float* __restrict__ logp_out,
                              int Npairs)
{
    int t = blockIdx.x * blockDim.x + threadIdx.x;
    if (t >= Npairs) return;

    const float4* W1T = reinterpret_cast<const float4*>(ws);                 // 2 float4 per j
    const float4* W2p = reinterpret_cast<const float4*>(ws + WS_W2_OFF);     // 3 float4 per j
    const float4* b2p = reinterpret_cast<const float4*>(ws + WS_B2_OFF);     // 3 float4

    // ---- load 2 rows of cond + seeds ----
    const float4* cp = reinterpret_cast<const float4*>(cond) + (size_t)t * 3;
    float4 ca = cp[0], cb = cp[1], cc = cp[2];
    float4 sd = reinterpret_cast<const float4*>(seed)[t];

    // row A: ca.x ca.y ca.z ca.w cb.x cb.y ; row B: cb.z cb.w cc.x cc.y cc.z cc.w
    f32x2 x0 = {ca.x, cb.z}, x1 = {ca.y, cb.w}, x2 = {ca.z, cc.x};
    f32x2 x3 = {ca.w, cc.y}, x4 = {cb.x, cc.z}, x5 = {cb.y, cc.w};

    // ---- MLP: rolled loop over PAIRS of hidden units. All 10 uniform
    // float4 weight loads for {j, j+1} issue up-front -> ONE lgkmcnt wait
    // window per 2 units, then ~34 pk-FMAs of issue. Doubles the
    // wait-amortization vs R8 without full-unroll register hoisting. ----
    float4 bq0 = b2p[0], bq1 = b2p[1], bq2 = b2p[2];
    f32x2 o[NOUT] = {
        bc2(bq0.x), bc2(bq0.y), bc2(bq0.z), bc2(bq0.w),
        bc2(bq1.x), bc2(bq1.y), bc2(bq1.z), bc2(bq1.w),
        bc2(bq2.x), bc2(bq2.y), bc2(bq2.z)
    };
#pragma unroll 1
    for (int j = 0; j < 32; j += 2) {
        // ---- all weight loads for units j and j+1 ----
        float4 wa0 = W1T[j * 2];
        float4 wb0 = W1T[j * 2 + 1];
        float4 wa1 = W1T[j * 2 + 2];
        float4 wb1 = W1T[j * 2 + 3];
        float4 q00 = W2p[j * 3];
        float4 q01 = W2p[j * 3 + 1];
        float4 q02 = W2p[j * 3 + 2];
        float4 q10 = W2p[j * 3 + 3];
        float4 q11 = W2p[j * 3 + 4];
        float4 q12 = W2p[j * 3 + 5];

        // ---- layer-1 for both units (independent chains) ----
        f32x2 acc0 = bc2(wb0.z);
        f32x2 acc1 = bc2(wb1.z);
        acc0 = fma2(x0, bc2(wa0.x), acc0);  acc1 = fma2(x0, bc2(wa1.x), acc1);
        acc0 = fma2(x1, bc2(wa0.y), acc0);  acc1 = fma2(x1, bc2(wa1.y), acc1);
        acc0 = fma2(x2, bc2(wa0.z), acc0);  acc1 = fma2(x2, bc2(wa1.z), acc1);
        acc0 = fma2(x3, bc2(wa0.w), acc0);  acc1 = fma2(x3, bc2(wa1.w), acc1);
        acc0 = fma2(x4, bc2(wb0.x), acc0);  acc1 = fma2(x4, bc2(wb1.x), acc1);
        acc0 = fma2(x5, bc2(wb0.y), acc0);  acc1 = fma2(x5, bc2(wb1.y), acc1);
        acc0 = __builtin_elementwise_max(acc0, (f32x2){0.0f, 0.0f});
        acc1 = __builtin_elementwise_max(acc1, (f32x2){0.0f, 0.0f});

        // ---- layer-2 scatter for both units ----
        o[0]  = fma2(acc0, bc2(q00.x), o[0]);
        o[1]  = fma2(acc0, bc2(q00.y), o[1]);
        o[2]  = fma2(acc0, bc2(q00.z), o[2]);
        o[3]  = fma2(acc0, bc2(q00.w), o[3]);
        o[4]  = fma2(acc0, bc2(q01.x), o[4]);
        o[5]  = fma2(acc0, bc2(q01.y), o[5]);
        o[6]  = fma2(acc0, bc2(q01.z), o[6]);
        o[7]  = fma2(acc0, bc2(q01.w), o[7]);
        o[8]  = fma2(acc0, bc2(q02.x), o[8]);
        o[9]  = fma2(acc0, bc2(q02.y), o[9]);
        o[10] = fma2(acc0, bc2(q02.z), o[10]);

        o[0]  = fma2(acc1, bc2(q10.x), o[0]);
        o[1]  = fma2(acc1, bc2(q10.y), o[1]);
        o[2]  = fma2(acc1, bc2(q10.z), o[2]);
        o[3]  = fma2(acc1, bc2(q10.w), o[3]);
        o[4]  = fma2(acc1, bc2(q11.x), o[4]);
        o[5]  = fma2(acc1, bc2(q11.y), o[5]);
        o[6]  = fma2(acc1, bc2(q11.z), o[6]);
        o[7]  = fma2(acc1, bc2(q11.w), o[7]);
        o[8]  = fma2(acc1, bc2(q12.x), o[8]);
        o[9]  = fma2(acc1, bc2(q12.y), o[9]);
        o[10] = fma2(acc1, bc2(q12.z), o[10]);
    }

    float oA[NOUT], oB[NOUT];
#pragma unroll
    for (int k = 0; k < NOUT; ++k) { oA[k] = o[k].x; oB[k] = o[k].y; }

    RowOut rA = epilogue(oA, sd.x, sd.y);
    RowOut rB = epilogue(oB, sd.z, sd.w);

    // ---- stores: z (N,2) as float4 per pair, log_p as float2 ----
    reinterpret_cast<float4*>(z_out)[t] = make_float4(rA.z0, rA.z1, rB.z0, rB.z1);
    reinterpret_cast<float2*>(logp_out)[t] = make_float2(rA.lp, rB.lp);
}

extern "C" void kernel_launch(void* const* d_in, const int* in_sizes, int n_in,
                              void* d_out, int out_size, void* d_ws, size_t ws_size,
                              hipStream_t stream)
{
    const float* cond = (const float*)d_in[0];
    const float* seed = (const float*)d_in[1];
    const float* W1   = (const float*)d_in[2];
    const float* b1   = (const float*)d_in[3];
    const float* W2   = (const float*)d_in[4];
    const float* b2   = (const float*)d_in[5];

    int N = in_sizes[1] / 2;   // randseed is (N,2)
    int Npairs = N / 2;

    float* ws = (float*)d_ws;
    float* z_out    = (float*)d_out;                   // first 2N floats
    float* logp_out = (float*)d_out + 2 * (size_t)N;   // next N floats

    pack_weights_kernel<<<1, 672, 0, stream>>>(W1, b1, W2, b2, ws);

    int block = 256;
    int grid = (Npairs + block - 1) / block;
    gmm_weighted_cond_kernel<<<grid, block, 0, stream>>>(
        cond, seed, ws, z_out, logp_out, Npairs);
}